// Round 3
// baseline (401.320 us; speedup 1.0000x reference)
//
#include <hip/hip_runtime.h>
#include <hip/hip_bf16.h>

typedef short short8 __attribute__((ext_vector_type(8)));
typedef float floatx4 __attribute__((ext_vector_type(4)));

#define B_  256
#define T_  512
#define D_  64
#define L_  32
#define H_  128
#define G4_ 512  // 4*H
#define PXS 516  // padded pre_x row stride (floats)

__device__ inline short f2bf(float f) {
    __hip_bfloat16 h = __float2bfloat16(f);
    union { __hip_bfloat16 h; short s; } u;
    u.h = h;
    return u.s;
}

__device__ inline float bf2f(short s) {
    union { float f; unsigned u; } u;
    u.u = ((unsigned)(unsigned short)s) << 16;
    return u.f;
}

__device__ inline float fast_sigmoid(float x) {
    return __builtin_amdgcn_rcpf(1.0f + __expf(-x));
}

__device__ inline float fast_tanh(float x) {
    float e = __expf(-2.0f * x);
    return 2.0f * __builtin_amdgcn_rcpf(1.0f + e) - 1.0f;
}

// One block per batch element. 512 threads = 8 waves.
// Wave w owns gate-columns [16w,16w+16) for ALL FOUR gate types -> i/f/g/o for
// a column land in one lane's accumulators -> in-register elementwise.
// Smooth software pipeline: exactly ONE barrier per step; window-(W+1) prep
// (x load / stage / x@Wih MFMAs / pre_x dump) spread across steps of window W;
// outputs buffered in LDS, single global store at kernel end.
__global__ __launch_bounds__(512, 2) void tamlstm_kernel(
    const float* __restrict__ xd,    // [B,T,D]
    const float* __restrict__ xs,    // [B,L]
    const float* __restrict__ Wih,   // [4H,D]
    const float* __restrict__ Whh,   // [4H,H]
    const float* __restrict__ Wzh,   // [4H,L]
    const float* __restrict__ bias,  // [4H]
    const float* __restrict__ Wout,  // [1,H]
    const float* __restrict__ bout,  // [1]
    float* __restrict__ out)         // [B,T]
{
    const int b    = blockIdx.x;
    const int tid  = threadIdx.x;
    const int w    = tid >> 6;    // wave 0..7
    const int lane = tid & 63;
    const int l15  = lane & 15;
    const int q    = lane >> 4;   // quad 0..3

    __shared__ __align__(16) float pre_x[16][PXS];   // 33 KB (wave-local r/w)
    __shared__ __align__(16) short x_lds[16][72];    // 2.25 KB staged x window
    __shared__ __align__(16) short h_ring[32][H_];   // 8 KB bf16 h history
    __shared__ float out_lds[T_];                    // 2 KB output buffer

    // zero h_ring (slot 0 = h_{-1} = 0)
    {
        int* hr = (int*)h_ring;  // 2048 ints
        #pragma unroll
        for (int i = 0; i < 4; ++i) hr[tid + 512 * i] = 0;
    }

    const int col = (w << 4) + l15;                 // hidden column 0..127

    // ---- B-fragments (bf16) in registers ----
    // B-frag element j = W[gate = col + 128e][k = 32s + 8q + j]
    short8 whh[4][4];  // [gate e][k-chunk s], K=128
    short8 wih[4][2];  // [e][s], K=64
    #pragma unroll
    for (int e = 0; e < 4; ++e) {
        const int g = col + (e << 7);
        const float* rh = Whh + g * H_;
        #pragma unroll
        for (int s = 0; s < 4; ++s) {
            const float* p = rh + s * 32 + q * 8;
            short8 v;
            #pragma unroll
            for (int j = 0; j < 8; ++j) v[j] = f2bf(p[j]);
            whh[e][s] = v;
        }
        const float* ri = Wih + g * D_;
        #pragma unroll
        for (int s = 0; s < 2; ++s) {
            const float* p = ri + s * 32 + q * 8;
            short8 v;
            #pragma unroll
            for (int j = 0; j < 8; ++j) v[j] = f2bf(p[j]);
            wih[e][s] = v;
        }
    }

    // ---- static part: bias + x_static @ Wzh^T ----
    float S[4];
    const float* xsb = xs + b * L_;
    #pragma unroll
    for (int e = 0; e < 4; ++e) {
        const int g = col + (e << 7);
        const float* wz = Wzh + g * L_;
        float a = bias[g];
        for (int l = 0; l < L_; ++l) a += xsb[l] * wz[l];
        S[e] = a;
    }
    const float wo0 = Wout[lane];
    const float wo1 = Wout[lane + 64];
    const float bo  = bout[0];

    // ---- prologue: stage x window 0 and compute its pre_x ----
    const float* xb = xd + (size_t)b * T_ * D_;
    {
        float2 x2 = ((const float2*)xb)[tid];        // rows 0..15
        unsigned pk = (unsigned)(unsigned short)f2bf(x2.x) |
                      ((unsigned)(unsigned short)f2bf(x2.y) << 16);
        const int e2 = tid * 2;
        *(unsigned*)&x_lds[e2 >> 6][e2 & 63] = pk;
    }
    __syncthreads();
    {
        floatx4 a0[4];
        #pragma unroll
        for (int e = 0; e < 4; ++e) a0[e] = (floatx4){0.f, 0.f, 0.f, 0.f};
        #pragma unroll
        for (int s = 0; s < 2; ++s) {
            short8 af = *(const short8*)&x_lds[l15][s * 32 + q * 8];
            #pragma unroll
            for (int e = 0; e < 4; ++e)
                a0[e] = __builtin_amdgcn_mfma_f32_16x16x32_bf16(af, wih[e][s], a0[e], 0, 0, 0);
        }
        #pragma unroll
        for (int e = 0; e < 4; ++e) {
            const int gcol = col + (e << 7);
            #pragma unroll
            for (int r = 0; r < 4; ++r) pre_x[q * 4 + r][gcol] = a0[e][r];
        }
    }

    float c = 0.0f;
    float2 xr;                 // in-flight x for next window
    floatx4 aw[4];             // next window's pre_x (this wave's cols)
    #pragma unroll
    for (int e = 0; e < 4; ++e) aw[e] = (floatx4){0.f, 0.f, 0.f, 0.f};

    for (int t = 0; t < T_; ++t) {
        const int tw = t & 15;
        const int t0 = t & ~15;                 // window base
        const bool havenext = (t0 + 16) < T_;   // window W+1 exists

        // ---------- pipelined window-(W+1) prep (uniform branches) ----------
        if (tw == 1 && havenext) {
            // issue global loads at step TOP: full step to hide HBM latency
            xr = ((const float2*)(xb + (t0 + 16) * D_))[tid];
        }
        if (tw == 3 && havenext) {
            unsigned pk = (unsigned)(unsigned short)f2bf(xr.x) |
                          ((unsigned)(unsigned short)f2bf(xr.y) << 16);
            const int e2 = tid * 2;
            *(unsigned*)&x_lds[e2 >> 6][e2 & 63] = pk;
            // visible to all waves after this step's end barrier
        }
        if (tw == 6 && havenext) {
            short8 af = *(const short8*)&x_lds[l15][q * 8];          // s=0
            #pragma unroll
            for (int e = 0; e < 4; ++e)
                aw[e] = __builtin_amdgcn_mfma_f32_16x16x32_bf16(af, wih[e][0],
                            (floatx4){0.f, 0.f, 0.f, 0.f}, 0, 0, 0);
        }
        if (tw == 10 && havenext) {
            short8 af = *(const short8*)&x_lds[l15][32 + q * 8];     // s=1
            #pragma unroll
            for (int e = 0; e < 4; ++e)
                aw[e] = __builtin_amdgcn_mfma_f32_16x16x32_bf16(af, wih[e][1], aw[e], 0, 0, 0);
        }
        if (tw == 13 && t >= 16) {
            // deferred output dot for window W-1 (2 timesteps per wave).
            // Slots were written >=14 steps ago, overwritten >=3 steps later.
            const int tp = t0 - 16 + (w << 1);
            const int s0 = (tp + 1) & 31;
            const int s1 = (tp + 2) & 31;
            float p0 = bf2f(h_ring[s0][lane]) * wo0 + bf2f(h_ring[s0][lane + 64]) * wo1;
            float p1 = bf2f(h_ring[s1][lane]) * wo0 + bf2f(h_ring[s1][lane + 64]) * wo1;
            #pragma unroll
            for (int d = 32; d >= 1; d >>= 1) {
                p0 += __shfl_xor(p0, d);
                p1 += __shfl_xor(p1, d);
            }
            if (lane == 0) {
                out_lds[tp]     = p0 + bo;
                out_lds[tp + 1] = p1 + bo;
            }
        }

        // ---------- recurrent MFMA: g += h_{t-1} @ Whh^T (two 2-deep chains) ----------
        const short8* hp = (const short8*)h_ring[t & 31];
        short8 af0 = hp[q];
        short8 af1 = hp[4 + q];
        short8 af2 = hp[8 + q];
        short8 af3 = hp[12 + q];
        floatx4 accA[4], accB[4];
        #pragma unroll
        for (int e = 0; e < 4; ++e) {
            accA[e] = __builtin_amdgcn_mfma_f32_16x16x32_bf16(af0, whh[e][0],
                          (floatx4){0.f, 0.f, 0.f, 0.f}, 0, 0, 0);
            accB[e] = __builtin_amdgcn_mfma_f32_16x16x32_bf16(af2, whh[e][2],
                          (floatx4){0.f, 0.f, 0.f, 0.f}, 0, 0, 0);
        }
        #pragma unroll
        for (int e = 0; e < 4; ++e) {
            accA[e] = __builtin_amdgcn_mfma_f32_16x16x32_bf16(af1, whh[e][1], accA[e], 0, 0, 0);
            accB[e] = __builtin_amdgcn_mfma_f32_16x16x32_bf16(af3, whh[e][3], accB[e], 0, 0, 0);
        }

        // pre_x reads (independent of MFMA results)
        const float px0 = pre_x[tw][col      ];
        const float px1 = pre_x[tw][col + 128];
        const float px2 = pre_x[tw][col + 256];
        const float px3 = pre_x[tw][col + 384];

        // ---------- elementwise ----------
        const float gi = accA[0].x + accB[0].x + px0 + S[0];
        const float gf = accA[1].x + accB[1].x + px1 + S[1];
        const float gg = accA[2].x + accB[2].x + px2 + S[2];
        const float go = accA[3].x + accB[3].x + px3 + S[3];
        const float is = fast_sigmoid(gi);
        const float fs = fast_sigmoid(gf);
        const float os = fast_sigmoid(go);
        const float tg = fast_tanh(gg);
        c = fs * c + is * tg;
        const float h = os * fast_tanh(c);

        if (lane < 16) h_ring[(t + 1) & 31][col] = f2bf(h);

        // dump next window's pre_x AFTER this window's last read (wave-local)
        if (tw == 15 && havenext) {
            #pragma unroll
            for (int e = 0; e < 4; ++e) {
                const int gcol = col + (e << 7);
                #pragma unroll
                for (int r = 0; r < 4; ++r) pre_x[q * 4 + r][gcol] = aw[e][r];
            }
        }

        __syncthreads();
    }

    // ---- epilogue: outputs for t' = 496..511, then one coalesced store ----
    {
        const int tp = T_ - 16 + (w << 1);
        const int s0 = (tp + 1) & 31;
        const int s1 = (tp + 2) & 31;
        float p0 = bf2f(h_ring[s0][lane]) * wo0 + bf2f(h_ring[s0][lane + 64]) * wo1;
        float p1 = bf2f(h_ring[s1][lane]) * wo0 + bf2f(h_ring[s1][lane + 64]) * wo1;
        #pragma unroll
        for (int d = 32; d >= 1; d >>= 1) {
            p0 += __shfl_xor(p0, d);
            p1 += __shfl_xor(p1, d);
        }
        if (lane == 0) {
            out_lds[tp]     = p0 + bo;
            out_lds[tp + 1] = p1 + bo;
        }
    }
    __syncthreads();
    out[b * T_ + tid] = out_lds[tid];
}

extern "C" void kernel_launch(void* const* d_in, const int* in_sizes, int n_in,
                              void* d_out, int out_size, void* d_ws, size_t ws_size,
                              hipStream_t stream) {
    const float* xd   = (const float*)d_in[0];
    const float* xs   = (const float*)d_in[1];
    const float* Wih  = (const float*)d_in[2];
    const float* Whh  = (const float*)d_in[3];
    const float* Wzh  = (const float*)d_in[4];
    const float* bias = (const float*)d_in[5];
    const float* Wout = (const float*)d_in[6];
    const float* bout = (const float*)d_in[7];
    float* o = (float*)d_out;
    hipLaunchKernelGGL(tamlstm_kernel, dim3(B_), dim3(512), 0, stream,
                       xd, xs, Wih, Whh, Wzh, bias, Wout, bout, o);
}